// Round 7
// baseline (341.082 us; speedup 1.0000x reference)
//
#include <hip/hip_runtime.h>

// ---- workspace layout (short elements) ----
// K pack  [h][7168][64] bf16                 @ 0
// V^T s0  [h][64][7168] bf16                 @ VB0
// V^T s1  [h][64][3584]                      @ VB1
// V^T s2  [h][64][1792]                      @ VB2
#define VB0 3670016L
#define VB1 7340032L
#define VB2 9175040L
// float region (offsets in floats from (float*)d_ws)
#define PO_OFF 5046272L                    // partial O: [512][128][64] fp32
#define PL_OFF (PO_OFF + 512L * 128 * 64)  // partial l: [512][128] fp32

typedef short bvec8 __attribute__((ext_vector_type(8)));
typedef float fvec16 __attribute__((ext_vector_type(16)));

#if defined(__has_builtin)
#if __has_builtin(__builtin_amdgcn_cvt_pk_bf16_f32)
#define HAVE_CVTPK 1
#endif
#if __has_builtin(__builtin_amdgcn_permlane32_swap)
#define HAVE_PLSWAP 1
#endif
#endif

static __device__ __forceinline__ unsigned pk2(float a, float b) {
#ifdef HAVE_CVTPK
  auto r = __builtin_amdgcn_cvt_pk_bf16_f32(a, b);  // single v_cvt_pk_bf16_f32
  unsigned u; __builtin_memcpy(&u, &r, 4);
  return u;
#else
  unsigned ua = (__float_as_uint(a) + 0x8000u) >> 16;
  unsigned ub = (__float_as_uint(b) + 0x8000u) & 0xffff0000u;
  return ua | ub;
#endif
}
static __device__ __forceinline__ void async16(const short* g, short* l) {
  __builtin_amdgcn_global_load_lds((const __attribute__((address_space(1))) unsigned*)(void*)g,
                                   (__attribute__((address_space(3))) unsigned*)(void*)l, 16, 0, 0);
}

// ---------------- fused packs: K bf16 copy + V^T bf16 transpose ----------------
__global__ __launch_bounds__(256) void pack_all(const float* __restrict__ k,
                                                const float* __restrict__ v,
                                                short* __restrict__ W) {
  __shared__ float tl[64][65];
  int b = blockIdx.x, t = threadIdx.x;
  if (b < 896) {  // K pack: [h][7168][64], 16 contiguous elements/thread
    int h = b / 112, tile = b % 112, i0 = tile * 64;
    int r = t >> 2, c = t & 3;
    const float* src = k + ((long)(i0 + r) * 8 + h) * 64 + c * 16;
    short* dst = W + ((long)h * 7168 + i0 + r) * 64 + c * 16;
    union { unsigned u[8]; bvec8 v[2]; } tw;
#pragma unroll
    for (int q4 = 0; q4 < 4; q4++) {
      float4 x = *(const float4*)(src + q4 * 4);
      tw.u[q4 * 2 + 0] = pk2(x.x, x.y);
      tw.u[q4 * 2 + 1] = pk2(x.z, x.w);
    }
    *(bvec8*)dst = tw.v[0];
    *(bvec8*)(dst + 8) = tw.v[1];
  } else {        // V^T pack
    int b2 = b - 896;
    int h, tile, dil, L; long base;
    if (b2 < 896)       { L = 7168; dil = 1; h = b2 / 112; tile = b2 % 112; base = VB0; }
    else if (b2 < 1344) { int bb = b2 - 896;  L = 3584; dil = 2; h = bb / 56; tile = bb % 56; base = VB1; }
    else                { int bb = b2 - 1344; L = 1792; dil = 4; h = bb / 28; tile = bb % 28; base = VB2; }
    int i0 = tile * 64;
    int row = t >> 2, c = t & 3;
    const float* src = v + ((long)(i0 + row) * dil * 8 + h) * 64;
#pragma unroll
    for (int cc = 0; cc < 4; cc++) {
      int d0 = c * 16 + cc * 4;
      float4 x = *(const float4*)(src + d0);
      tl[row][d0 + 0] = x.x; tl[row][d0 + 1] = x.y;
      tl[row][d0 + 2] = x.z; tl[row][d0 + 3] = x.w;
    }
    __syncthreads();
    int d = t >> 2, part = t & 3;
    union { unsigned u[8]; bvec8 v[2]; } tw;
#pragma unroll
    for (int u2 = 0; u2 < 8; u2++)
      tw.u[u2] = pk2(tl[part * 16 + 2 * u2][d], tl[part * 16 + 2 * u2 + 1][d]);
    short* dst = W + base + ((long)h * 64 + d) * L + i0 + part * 16;
    *(bvec8*)dst = tw.v[0];
    *(bvec8*)(dst + 8) = tw.v[1];
  }
}

// cross-half P exchange
#ifdef HAVE_PLSWAP
#define PEXCH(fu, da0, da1, db0, db1)                                              \
  do {                                                                             \
    auto rr0 = __builtin_amdgcn_permlane32_swap((int)(da0), (int)(db0), false, false); \
    auto rr1 = __builtin_amdgcn_permlane32_swap((int)(da1), (int)(db1), false, false); \
    __builtin_memcpy(&fu.u4[0], &rr0, 4);                                          \
    __builtin_memcpy(&fu.u4[2], (const char*)&rr0 + 4, 4);                         \
    __builtin_memcpy(&fu.u4[1], &rr1, 4);                                          \
    __builtin_memcpy(&fu.u4[3], (const char*)&rr1 + 4, 4);                         \
  } while (0)
#else
#define PEXCH(fu, da0, da1, db0, db1)                                              \
  do {                                                                             \
    unsigned s0 = hb ? (da0) : (db0), s1 = hb ? (da1) : (db1);                     \
    unsigned x0 = __shfl_xor(s0, 32), x1 = __shfl_xor(s1, 32);                     \
    fu.u4[0] = hb ? x0 : (da0);  fu.u4[1] = hb ? x1 : (da1);                       \
    fu.u4[2] = hb ? (db0) : x0;  fu.u4[3] = hb ? (db1) : x1;                       \
  } while (0)
#endif

// one softmax slot (key 16-slot SP of this wave's key-half):
// exp2 on 8 scores + l-accumulate + P pack/exchange + 2 PV MFMAs
#define SOFTMAX_PV(SP)                                                             \
  do {                                                                             \
    const int r0_ = (SP) * 8;                                                      \
    float p[8];                                                                    \
    _Pragma("unroll") for (int u = 0; u < 8; u++)                                  \
        p[u] = __builtin_amdgcn_exp2f(Sa[r0_ + u]);                                \
    lacc += ((p[0] + p[1]) + (p[2] + p[3])) + ((p[4] + p[5]) + (p[6] + p[7]));     \
    unsigned da0 = pk2(p[0], p[1]), da1 = pk2(p[2], p[3]);                         \
    unsigned db0 = pk2(p[4], p[5]), db1 = pk2(p[6], p[7]);                         \
    union { unsigned u4[4]; bvec8 v; } fu;                                         \
    PEXCH(fu, da0, da1, db0, db1);                                                 \
    __builtin_amdgcn_s_setprio(1);                                                 \
    Oa[0] = __builtin_amdgcn_mfma_f32_32x32x16_bf16(vf[(SP)], fu.v, Oa[0], 0, 0, 0);     \
    Oa[1] = __builtin_amdgcn_mfma_f32_32x32x16_bf16(vf[2 + (SP)], fu.v, Oa[1], 0, 0, 0); \
    __builtin_amdgcn_s_setprio(0);                                                 \
  } while (0)

// --------------------- main flash attention (S^T form) ---------------------
// R15: 8-wave blocks (512 thr) — TLP fix. R6 analysis: grid 768 = 3 blocks/CU
// hard-caps occupancy at 3 waves/SIMD; per-wave latency chains can't be hidden
// (R10/R11/R14 all ~70us regardless of schedule). Here wave w takes q-block
// (w&3, 32 q-rows) x key-half (w>>2, 32 of 64 keys) of the SAME shared LDS
// tile: per-wave work halves, waves/SIMD double (6). Indexing + cross-half
// merge epilogue verbatim from R12 (verification-passed in R4). Pipeline =
// R14 (3 buffers, K-register prefetch, one mid-iteration vmcnt(0)+s_barrier).
__global__ __launch_bounds__(512, 6) void attn_kern(const float* __restrict__ q,
                                                    const short* __restrict__ W,
                                                    float* __restrict__ out,
                                                    float* __restrict__ PO,
                                                    float* __restrict__ PL) {
  int b = blockIdx.x;
  int h, q0, dil, kt0, L; long vbo;
  if (b < 256)      { int sp = b & 3; h = (b >> 2) & 7; int qt = b >> 5;
                      q0 = qt * 128;        dil = 1; L = 7168; vbo = VB0; kt0 = sp * 28; }
  else if (b < 512) { int i = b - 256; int sp = i & 1; h = (i >> 1) & 7; int qt = i >> 4;
                      q0 = 1024 + qt * 128; dil = 2; L = 3584; vbo = VB1; kt0 = sp * 28; }
  else              { int i = b - 512; h = i & 7; int qt = i >> 3;
                      q0 = 3072 + qt * 128; dil = 4; L = 1792; vbo = VB2; kt0 = 0; }
  const short* kb = W + (long)h * 7168 * 64;
  const short* vt = W + vbo + (long)h * 64 * L;
  const int dil64 = dil * 64;

  __shared__ __attribute__((aligned(16))) short sK[3][4096];  // XOR-swizzled
  __shared__ __attribute__((aligned(16))) short sV[3][4096];  // XOR-swizzled
  __shared__ float sLm[4][64];                                // l merge scratch
  short* sKf = &sK[0][0];
  short* sVf = &sV[0][0];

  int t = threadIdx.x, lane = t & 63, w = t >> 6;
  int ln = lane & 31, hb = lane >> 5;
  int qh = w & 3, kbh = w >> 2;

  // Q as B-operand (n = q-row = ln, k-els d = 16*ks + 8*hb + j), scale folds 1/8 * log2(e)
  bvec8 qb[4];
  {
    const float* qp = q + ((long)(q0 + qh * 32 + ln) * 8 + h) * 64 + 8 * hb;
    const float qs = 0.125f * 1.44269504088896f;
#pragma unroll
    for (int ks = 0; ks < 4; ks++) {
      union { unsigned u[4]; bvec8 v; } qu;
#pragma unroll
      for (int jj = 0; jj < 4; jj++)
        qu.u[jj] = pk2(qs * qp[ks * 16 + 2 * jj], qs * qp[ks * 16 + 2 * jj + 1]);
      qb[ks] = qu.v;
    }
  }

  // staging: 8 waves x 8 rows; per-lane incrementing global pointers
  int srow = lane >> 3, sch = (lane & 7) ^ srow;
  const long kstep = 64L * dil64;
  const short* gk; const short* gv;
  {
    int row = w * 8 + srow;
    long kb0 = (long)kt0 * 64;
    gk = kb + (kb0 + row) * dil64 + sch * 8;
    gv = vt + (long)row * L + kb0 + sch * 8;
  }
  const int ldoff = w * 512;
  auto stage = [&](int bo2) {
    async16(gk, sKf + bo2 + ldoff);
    async16(gv, sVf + bo2 + ldoff);
    gk += kstep; gv += 64;
  };

  stage(0);     // tile 0 -> buf 0
  stage(4096);  // tile 1 -> buf 1
  asm volatile("s_waitcnt vmcnt(2)" ::: "memory");  // own tile-0 loads done
  __builtin_amdgcn_s_barrier();                     // all waves: tile 0 complete
  asm volatile("" ::: "memory");

  // LDS fragment offsets (XOR swizzle: stored col = chunk ^ (row&7)) — R12-verified
  int koffK[4], koffV[4];
#pragma unroll
  for (int ks = 0; ks < 4; ks++)
    koffK[ks] = (kbh * 32 + ln) * 64 + (((2 * ks + hb) ^ (ln & 7)) * 8);
#pragma unroll
  for (int dh = 0; dh < 2; dh++)
#pragma unroll
    for (int sp = 0; sp < 2; sp++)
      koffV[dh * 2 + sp] = (dh * 32 + ln) * 64 + (((2 * (2 * kbh + sp) + hb) ^ (ln & 7)) * 8);

  // prefetch tile 0's K fragments (this wave's key-half) into registers
  bvec8 kf[4];
#pragma unroll
  for (int i = 0; i < 4; i++) kf[i] = *(const bvec8*)(sKf + koffK[i]);

  fvec16 Oa[2];
  float lacc = 0.f;
#pragma unroll
  for (int i = 0; i < 16; i++) { Oa[0][i] = 0.f; Oa[1][i] = 0.f; }

  int bc = 0, bn = 4096, bs = 8192;
  for (int it = 0; it < 28; it++) {
    // V^T fragments (key-half) for tile it: 4 ds_read hide under QK MFMAs
    bvec8 vf[4];
#pragma unroll
    for (int i = 0; i < 4; i++) vf[i] = *(const bvec8*)(sVf + bc + koffV[i]);

    // S^T = K_half * Q^T from prefetched kf registers — no LDS wait at head
    fvec16 Sa;
#pragma unroll
    for (int i = 0; i < 16; i++) Sa[i] = 0.f;
    __builtin_amdgcn_s_setprio(1);
#pragma unroll
    for (int ks = 0; ks < 4; ks++)
      Sa = __builtin_amdgcn_mfma_f32_32x32x16_bf16(kf[ks], qb[ks], Sa, 0, 0, 0);
    __builtin_amdgcn_s_setprio(0);

    SOFTMAX_PV(0);

    // tile it+1 DMA complete (own loads drained + barrier joins all waves);
    // every wave consumed its tile it-1 fragments -> buf[(it+2)%3] free
    asm volatile("s_waitcnt vmcnt(0)" ::: "memory");
    __builtin_amdgcn_s_barrier();
    asm volatile("" ::: "memory");

    if (it < 26) stage(bs);  // tile it+2
    if (it < 27) {           // prefetch tile it+1 K fragments (hide under slot 1)
#pragma unroll
      for (int i = 0; i < 4; i++) kf[i] = *(const bvec8*)(sKf + bn + koffK[i]);
    }

    SOFTMAX_PV(1);

    bc = bn; bn = bs; bs = (bs == 8192) ? 0 : bs + 4096;
  }

  // ---- epilogue: merge the two key-half waves (w and w^4 share q-block qh) ----
  // l[ln]: this lane's 16 key-rows + partner hb's 16 (R12-verified)
  float lt = lacc + __shfl_xor(lacc, 32);

  __syncthreads();  // all tile-27 LDS reads done; buffers reusable as scratch
  if (kbh) {        // key-half-1 waves publish partials (lane-major: conflict-free)
    float* dst = (qh < 3) ? ((float*)sKf + qh * 2048) : (float*)sVf;
#pragma unroll
    for (int dh = 0; dh < 2; dh++)
#pragma unroll
      for (int r = 0; r < 16; r++)
        dst[(dh * 16 + r) * 64 + lane] = Oa[dh][r];
    sLm[qh][lane] = lt;
  }
  __syncthreads();
  if (!kbh) {       // key-half-0 waves reduce + store
    const float* src = (qh < 3) ? ((const float*)sKf + qh * 2048) : (const float*)sVf;
#pragma unroll
    for (int dh = 0; dh < 2; dh++)
#pragma unroll
      for (int r = 0; r < 16; r++)
        Oa[dh][r] += src[(dh * 16 + r) * 64 + lane];
    lt += sLm[qh][lane];

    // O^T C-layout: qcol = ln, d = 32*dh + 8*r2 + 4*hb + r3 (R12-verified)
    int wl = qh * 32 + ln;
    if (b < 512) {
      float* po = PO + ((long)b * 128 + wl) * 64;
#pragma unroll
      for (int dh = 0; dh < 2; dh++)
#pragma unroll
        for (int r2 = 0; r2 < 4; r2++) {
          float4 x = { Oa[dh][r2 * 4 + 0], Oa[dh][r2 * 4 + 1],
                       Oa[dh][r2 * 4 + 2], Oa[dh][r2 * 4 + 3] };
          *(float4*)(po + dh * 32 + r2 * 8 + hb * 4) = x;
        }
      if (hb == 0) PL[(long)b * 128 + wl] = lt;
    } else {
      float inv = 1.f / lt;
      float* op = out + ((long)(q0 + wl) * 8 + h) * 64;
#pragma unroll
      for (int dh = 0; dh < 2; dh++)
#pragma unroll
        for (int r2 = 0; r2 < 4; r2++) {
          float4 x = { Oa[dh][r2 * 4 + 0] * inv, Oa[dh][r2 * 4 + 1] * inv,
                       Oa[dh][r2 * 4 + 2] * inv, Oa[dh][r2 * 4 + 3] * inv };
          *(float4*)(op + dh * 32 + r2 * 8 + hb * 4) = x;
        }
    }
  }
}

// --------------- combine partials (seg0: 4 splits, seg1: 2 splits) ---------------
__global__ __launch_bounds__(256) void combine_kern(const float* __restrict__ PO,
                                                    const float* __restrict__ PL,
                                                    float* __restrict__ out) {
  int g = blockIdx.x, t = threadIdx.x;
  int base_b, nsp, q0, h;
  if (g < 64) { int qt = g >> 3; h = g & 7; base_b = qt * 32 + h * 4; nsp = 4; q0 = qt * 128; }
  else { int gi = g - 64; int qt = gi >> 3; h = gi & 7; base_b = 256 + qt * 16 + h * 2; nsp = 2; q0 = 1024 + qt * 128; }
  int r = t >> 1, ch = (t & 1) * 32;
  float lt = 0.f;
  for (int sp = 0; sp < nsp; sp++) lt += PL[(long)(base_b + sp) * 128 + r];
  float inv = 1.f / lt;
  float4 acc[8];
#pragma unroll
  for (int j = 0; j < 8; j++) { acc[j].x = 0.f; acc[j].y = 0.f; acc[j].z = 0.f; acc[j].w = 0.f; }
  for (int sp = 0; sp < nsp; sp++) {
    const float4* pb = (const float4*)(PO + ((long)(base_b + sp) * 128 + r) * 64 + ch);
#pragma unroll
    for (int j = 0; j < 8; j++) {
      float4 x = pb[j];
      acc[j].x += x.x; acc[j].y += x.y; acc[j].z += x.z; acc[j].w += x.w;
    }
  }
  float4* op = (float4*)(out + ((long)(q0 + r) * 8 + h) * 64 + ch);
#pragma unroll
  for (int j = 0; j < 8; j++) {
    float4 x = { acc[j].x * inv, acc[j].y * inv, acc[j].z * inv, acc[j].w * inv };
    op[j] = x;
  }
}

extern "C" void kernel_launch(void* const* d_in, const int* in_sizes, int n_in,
                              void* d_out, int out_size, void* d_ws, size_t ws_size,
                              hipStream_t stream) {
  const float* q = (const float*)d_in[0];
  const float* k = (const float*)d_in[1];
  const float* v = (const float*)d_in[2];
  float* out = (float*)d_out;
  short* W = (short*)d_ws;                 // ~37.3 MB workspace total (proven)
  float* PO = (float*)d_ws + PO_OFF;
  float* PL = (float*)d_ws + PL_OFF;

  pack_all<<<2464, 256, 0, stream>>>(k, v, W);
  attn_kern<<<768, 512, 0, stream>>>(q, W, out, PO, PL);
  combine_kern<<<192, 256, 0, stream>>>(PO, PL, out);
}